// Round 1
// baseline (848.070 us; speedup 1.0000x reference)
//
#include <hip/hip_runtime.h>

// Sparse graph attention (fp32):
//   x = (q[i0] . k[i1]) / 8 ; y = eigs[i0] . eigs[i1]
//   e = min(exp(x + exp(lambda0)*y), 5)
//   denom = segment_sum(e, i0); denom==0 -> 1
//   out[i0,:] += (e/denom[i0]) * v[i1,:]
//
// One 64-lane wave per edge; lane = channel. All per-row global accesses are
// 256B coalesced bursts. Dot product via 6-step shfl_xor reduce.

#define HD 64
#define ED 32

__global__ void edge_logits_kernel(const float* __restrict__ q,
                                   const float* __restrict__ k,
                                   const float* __restrict__ eigs,
                                   const float* __restrict__ lambda0,
                                   const int* __restrict__ idx,
                                   float* __restrict__ e_out,
                                   float* __restrict__ denom,
                                   int n_edges) {
    long long gid = (long long)blockIdx.x * blockDim.x + threadIdx.x;
    int edge = (int)(gid >> 6);
    int lane = (int)(gid & 63);
    if (edge >= n_edges) return;

    int i0 = idx[edge];            // destination (row)
    int i1 = idx[n_edges + edge];  // source (col)

    float expL = __expf(lambda0[0]);

    // lane d: q[i0][d]*k[i1][d]/8  (+ eigs term on lanes 0..31)
    float c = q[(long long)i0 * HD + lane] * k[(long long)i1 * HD + lane] * 0.125f;
    if (lane < ED)
        c += expL * eigs[(long long)i0 * ED + lane] * eigs[(long long)i1 * ED + lane];

    // wave-64 butterfly reduce
    #pragma unroll
    for (int off = 32; off > 0; off >>= 1)
        c += __shfl_xor(c, off, 64);

    if (lane == 0) {
        float e = fminf(__expf(c), 5.0f);   // clip(exp(s), -5, 5): exp>0 so only upper bound binds
        e_out[edge] = e;
        atomicAdd(&denom[i0], e);
    }
}

__global__ void edge_scatter_kernel(const float* __restrict__ v,
                                    const int* __restrict__ idx,
                                    const float* __restrict__ e_in,
                                    const float* __restrict__ denom,
                                    float* __restrict__ out,
                                    int n_edges) {
    long long gid = (long long)blockIdx.x * blockDim.x + threadIdx.x;
    int edge = (int)(gid >> 6);
    int lane = (int)(gid & 63);
    if (edge >= n_edges) return;

    int i0 = idx[edge];
    int i1 = idx[n_edges + edge];

    float d = denom[i0];              // broadcast load (same addr across wave)
    d = (d == 0.0f) ? 1.0f : d;
    float w = e_in[edge] / d;         // broadcast load

    // coalesced 256B atomic burst per wave
    atomicAdd(&out[(long long)i0 * HD + lane], w * v[(long long)i1 * HD + lane]);
}

extern "C" void kernel_launch(void* const* d_in, const int* in_sizes, int n_in,
                              void* d_out, int out_size, void* d_ws, size_t ws_size,
                              hipStream_t stream) {
    const float* q       = (const float*)d_in[0];
    const float* k       = (const float*)d_in[1];
    const float* v       = (const float*)d_in[2];
    const float* eigs    = (const float*)d_in[3];
    const float* lambda0 = (const float*)d_in[4];
    const int*   idx     = (const int*)d_in[5];   // [2, E], int32 (JAX x64 disabled)

    const int n_edges = in_sizes[5] / 2;
    const int n_nodes = in_sizes[0] / HD;

    float* e_buf = (float*)d_ws;          // [E]
    float* denom = e_buf + n_edges;       // [N]

    hipMemsetAsync(denom, 0, (size_t)n_nodes * sizeof(float), stream);
    hipMemsetAsync(d_out, 0, (size_t)out_size * sizeof(float), stream);

    const int block = 256;  // 4 waves/block
    long long threads = (long long)n_edges * 64;
    int grid = (int)((threads + block - 1) / block);

    edge_logits_kernel<<<grid, block, 0, stream>>>(q, k, eigs, lambda0, idx,
                                                   e_buf, denom, n_edges);
    edge_scatter_kernel<<<grid, block, 0, stream>>>(v, idx, e_buf, denom,
                                                    (float*)d_out, n_edges);
}

// Round 2
// 669.382 us; speedup vs baseline: 1.2669x; 1.2669x over previous
//
#include <hip/hip_runtime.h>

// Sparse graph attention (fp32), merged single edge pass + node normalize:
//   e = min(exp(q[i0].k[i1]/8 + exp(l0)*eigs[i0].eigs[i1]), 5)
//   denom[i0] += e        (atomic, lane 0)
//   out[i0,:] += e * v[i1,:]   (unnormalized atomic scatter, 64-lane burst)
// then out[r,:] /= (denom[r]==0 ? 1 : denom[r])
//
// One 64-lane wave per edge; lane = channel. Every per-row global access is a
// 256B coalesced burst. Dot via 6-step shfl_xor butterfly (leaves the full sum
// in ALL lanes, so no re-broadcast is needed before the scatter).

#define HD 64
#define ED 32

__global__ void edge_fused_kernel(const float* __restrict__ q,
                                  const float* __restrict__ k,
                                  const float* __restrict__ v,
                                  const float* __restrict__ eigs,
                                  const float* __restrict__ lambda0,
                                  const int* __restrict__ idx,
                                  float* __restrict__ denom,
                                  float* __restrict__ out,
                                  int n_edges) {
    long long gid = (long long)blockIdx.x * blockDim.x + threadIdx.x;
    int edge = (int)(gid >> 6);
    int lane = (int)(gid & 63);
    if (edge >= n_edges) return;

    int i0 = idx[edge];            // destination (row)
    int i1 = idx[n_edges + edge];  // source (col)

    float expL = __expf(lambda0[0]);

    // lane d: q[i0][d]*k[i1][d]/8  (+ eigs term on lanes 0..31)
    float c = q[(long long)i0 * HD + lane] * k[(long long)i1 * HD + lane] * 0.125f;
    if (lane < ED)
        c += expL * eigs[(long long)i0 * ED + lane] * eigs[(long long)i1 * ED + lane];

    // wave-64 butterfly reduce -> every lane holds the full sum
    #pragma unroll
    for (int off = 32; off > 0; off >>= 1)
        c += __shfl_xor(c, off, 64);

    float e = fminf(__expf(c), 5.0f);   // exp>0, only the upper clip binds

    if (lane == 0) atomicAdd(&denom[i0], e);

    // coalesced 256B atomic burst per wave (unnormalized)
    atomicAdd(&out[(long long)i0 * HD + lane],
              e * v[(long long)i1 * HD + lane]);
}

// out[r,:] /= denom[r]  (denom==0 -> 1). float4 per thread.
__global__ void normalize_kernel(float* __restrict__ out,
                                 const float* __restrict__ denom,
                                 int n_nodes) {
    int t = blockIdx.x * blockDim.x + threadIdx.x;         // one float4
    int total = n_nodes * (HD / 4);
    if (t >= total) return;
    int row = t / (HD / 4);
    float d = denom[row];
    float inv = (d == 0.0f) ? 1.0f : __frcp_rn(d);
    float4* o4 = (float4*)out;
    float4 x = o4[t];
    x.x *= inv; x.y *= inv; x.z *= inv; x.w *= inv;
    o4[t] = x;
}

extern "C" void kernel_launch(void* const* d_in, const int* in_sizes, int n_in,
                              void* d_out, int out_size, void* d_ws, size_t ws_size,
                              hipStream_t stream) {
    const float* q       = (const float*)d_in[0];
    const float* k       = (const float*)d_in[1];
    const float* v       = (const float*)d_in[2];
    const float* eigs    = (const float*)d_in[3];
    const float* lambda0 = (const float*)d_in[4];
    const int*   idx     = (const int*)d_in[5];   // [2, E], int32

    const int n_edges = in_sizes[5] / 2;
    const int n_nodes = in_sizes[0] / HD;

    float* denom = (float*)d_ws;          // [N]

    hipMemsetAsync(denom, 0, (size_t)n_nodes * sizeof(float), stream);
    hipMemsetAsync(d_out, 0, (size_t)out_size * sizeof(float), stream);

    const int block = 256;  // 4 waves/block
    long long threads = (long long)n_edges * 64;
    int grid = (int)((threads + block - 1) / block);

    edge_fused_kernel<<<grid, block, 0, stream>>>(q, k, v, eigs, lambda0, idx,
                                                  denom, (float*)d_out, n_edges);

    int n4 = n_nodes * (HD / 4);
    normalize_kernel<<<(n4 + 255) / 256, 256, 0, stream>>>((float*)d_out, denom,
                                                           n_nodes);
}